// Round 1
// baseline (191.879 us; speedup 1.0000x reference)
//
#include <hip/hip_runtime.h>
#include <math.h>

// NEG (negative-sampling) loss.
// V=50000, E=256, B=4096, W=5, S=15. Pair j (j in [0, B*W)):
//   inp  = in_embed[input_labels[j % B]]            (tile, NOT interleave)
//   out  = out_embed[out_labels.flat[j]]
//   noise_s = out_embed[noise_labels[j, s]]
//   contrib_j = log_sigmoid(<inp,out>) + sum_s log_sigmoid(-<inp,noise_s>)
//   loss = -(sum_j contrib_j) / B
// One 64-lane wave per pair: lane holds float4 (4*64 = 256 = E).

#define EDIM 256
#define SNEG 15

__device__ __forceinline__ float wave_reduce_sum(float v) {
    // butterfly over 64 lanes; result in every lane
    v += __shfl_xor(v, 32, 64);
    v += __shfl_xor(v, 16, 64);
    v += __shfl_xor(v, 8, 64);
    v += __shfl_xor(v, 4, 64);
    v += __shfl_xor(v, 2, 64);
    v += __shfl_xor(v, 1, 64);
    return v;
}

__device__ __forceinline__ float log_sigmoid(float x) {
    // stable: min(x,0) - log1p(exp(-|x|))
    return fminf(x, 0.0f) - log1pf(__expf(-fabsf(x)));
}

__global__ void zero_acc_kernel(double* acc) { *acc = 0.0; }

__global__ __launch_bounds__(256) void neg_loss_kernel(
    const float* __restrict__ in_w,    // [V, E]
    const float* __restrict__ out_w,   // [V, E]
    const int* __restrict__ in_lab,    // [B]
    const int* __restrict__ out_lab,   // [B*W] (row-major flat of [B, W])
    const int* __restrict__ noise_lab, // [B*W, S]
    double* __restrict__ acc,
    int B, int BW)
{
    __shared__ float wave_sums[4];
    const int wave = threadIdx.x >> 6;
    const int lane = threadIdx.x & 63;
    const int j = blockIdx.x * 4 + wave;

    float c = 0.0f;
    if (j < BW) {
        const int in_row = in_lab[j % B];  // tile semantics
        const float4 vin =
            *(const float4*)(in_w + (size_t)in_row * EDIM + lane * 4);

        // positive pair
        {
            const int row = out_lab[j];
            const float4 vo =
                *(const float4*)(out_w + (size_t)row * EDIM + lane * 4);
            float d = vin.x * vo.x + vin.y * vo.y + vin.z * vo.z + vin.w * vo.w;
            d = wave_reduce_sum(d);
            c += log_sigmoid(d);
        }

        // noise samples: score = -<inp, noise_row>
        const int* nl = noise_lab + (size_t)j * SNEG;
#pragma unroll
        for (int s = 0; s < SNEG; ++s) {
            const int row = nl[s];
            const float4 vo =
                *(const float4*)(out_w + (size_t)row * EDIM + lane * 4);
            float d = vin.x * vo.x + vin.y * vo.y + vin.z * vo.z + vin.w * vo.w;
            d = wave_reduce_sum(d);
            c += log_sigmoid(-d);
        }
    }

    if (lane == 0) wave_sums[wave] = c;
    __syncthreads();
    if (threadIdx.x == 0) {
        const float blocksum =
            wave_sums[0] + wave_sums[1] + wave_sums[2] + wave_sums[3];
        atomicAdd(acc, (double)blocksum);  // double accum: keeps |err| << 3.6
    }
}

__global__ void finalize_kernel(const double* acc, float* out, double invB) {
    *out = (float)(-(*acc) * invB);
}

extern "C" void kernel_launch(void* const* d_in, const int* in_sizes, int n_in,
                              void* d_out, int out_size, void* d_ws, size_t ws_size,
                              hipStream_t stream) {
    const float* in_w     = (const float*)d_in[0];
    const float* out_w    = (const float*)d_in[1];
    const int*   in_lab   = (const int*)d_in[2];
    const int*   out_lab  = (const int*)d_in[3];
    const int*   noise_lab= (const int*)d_in[4];
    // d_in[5] = num_sampled (scalar) — S is fixed at 15 per problem spec.

    const int B  = in_sizes[2];   // 4096
    const int BW = in_sizes[3];   // B*W = 20480

    double* acc = (double*)d_ws;  // 8 bytes of workspace; re-poisoned each call
    float*  out = (float*)d_out;

    zero_acc_kernel<<<1, 1, 0, stream>>>(acc);

    const int blocks = (BW + 3) / 4;  // 4 waves (pairs) per 256-thread block
    neg_loss_kernel<<<blocks, 256, 0, stream>>>(
        in_w, out_w, in_lab, out_lab, noise_lab, acc, B, BW);

    finalize_kernel<<<1, 1, 0, stream>>>(acc, out, 1.0 / (double)B);
}

// Round 2
// 157.818 us; speedup vs baseline: 1.2158x; 1.2158x over previous
//
#include <hip/hip_runtime.h>
#include <math.h>

// NEG (negative-sampling) loss. V=50000, E=256, B=4096, W=5, S=15.
// Pair j in [0, B*W):
//   inp  = in_embed[input_labels[j % B]]      (tile semantics, NOT interleave)
//   out  = out_embed[out_labels.flat[j]]
//   noise_s = out_embed[noise_labels[j, s]]
//   contrib_j = logsig(<inp,out>) + sum_s logsig(-<inp,noise_s>)
//   loss = -(sum_j contrib_j) / B
//
// R2 structure: one wave per pair; 16 dots per pair = 4 rounds x 4 concurrent
// dots (one per 16-lane quarter-wave). Lane t of a quarter owns 16 elements of
// the 256-elem row: float4 at element offset k*64 + t*4, k=0..3 -> each
// (quarter, k) access is a contiguous 256B segment (fully coalesced).
// Cuts per-pair reduce ops 192->36 and logsig 16x7->4x6 vs R1.

#define EDIM 256
#define SNEG 15

__device__ __forceinline__ float dot4(float4 a, float4 b) {
    return a.x * b.x + a.y * b.y + a.z * b.z + a.w * b.w;
}

__device__ __forceinline__ float log_sigmoid_fast(float x) {
    // min(x,0) - log(1 + exp(-|x|)); arg of log in (1,2] -> accurate & branch-free
    return fminf(x, 0.0f) - __logf(1.0f + __expf(-fabsf(x)));
}

__global__ __launch_bounds__(256) void neg_loss_kernel(
    const float* __restrict__ in_w,     // [V, E]
    const float* __restrict__ out_w,    // [V, E]
    const int* __restrict__ in_lab,     // [B]
    const int* __restrict__ out_lab,    // [B*W]
    const int* __restrict__ noise_lab,  // [B*W, S]
    float* __restrict__ partials,       // [gridDim.x]
    int B, int BW)
{
    __shared__ float wave_sums[4];
    const int wave = threadIdx.x >> 6;
    const int lane = threadIdx.x & 63;
    const int q    = lane >> 4;   // quarter-wave id: which dot in the round
    const int t    = lane & 15;   // position within quarter

    const int j = blockIdx.x * 4 + wave;

    float c = 0.0f;
    if (j < BW) {
        const int jm = (B & (B - 1)) == 0 ? (j & (B - 1)) : (j % B);
        const int in_row = in_lab[jm];

        // vin slice for lane t: float4s at element offsets k*64 + t*4
        const float* vin_base = in_w + (size_t)in_row * EDIM + t * 4;
        const float4 vi0 = *(const float4*)(vin_base + 0 * 64);
        const float4 vi1 = *(const float4*)(vin_base + 1 * 64);
        const float4 vi2 = *(const float4*)(vin_base + 2 * 64);
        const float4 vi3 = *(const float4*)(vin_base + 3 * 64);

        const int* nl = noise_lab + (size_t)j * SNEG;
        const int out_row = out_lab[j];

#pragma unroll
        for (int r = 0; r < 4; ++r) {
            const int d = r * 4 + q;                       // dot index 0..15
            const int row = (d == 0) ? out_row : nl[d - 1];
            const float* rb = out_w + (size_t)row * EDIM + t * 4;
            const float4 v0 = *(const float4*)(rb + 0 * 64);
            const float4 v1 = *(const float4*)(rb + 1 * 64);
            const float4 v2 = *(const float4*)(rb + 2 * 64);
            const float4 v3 = *(const float4*)(rb + 3 * 64);

            float s = dot4(vi0, v0) + dot4(vi1, v1) + dot4(vi2, v2) + dot4(vi3, v3);
            // reduce across the 16 lanes of this quarter (xor stays in-quarter)
            s += __shfl_xor(s, 1, 64);
            s += __shfl_xor(s, 2, 64);
            s += __shfl_xor(s, 4, 64);
            s += __shfl_xor(s, 8, 64);

            const float x = (d == 0) ? s : -s;   // positive pair vs noise
            c += log_sigmoid_fast(x);
        }

        // sum the 4 quarter-accumulators across the wave
        c += __shfl_xor(c, 16, 64);
        c += __shfl_xor(c, 32, 64);
    }

    if (lane == 0) wave_sums[wave] = c;
    __syncthreads();
    if (threadIdx.x == 0) {
        partials[blockIdx.x] =
            wave_sums[0] + wave_sums[1] + wave_sums[2] + wave_sums[3];
    }
}

__global__ __launch_bounds__(256) void reduce_kernel(
    const float* __restrict__ partials, float* __restrict__ out,
    int n, double invB)
{
    __shared__ double wsum[4];
    double t = 0.0;
    for (int i = threadIdx.x; i < n; i += 256) t += (double)partials[i];
    // wave butterfly on double
    t += __shfl_xor(t, 32, 64);
    t += __shfl_xor(t, 16, 64);
    t += __shfl_xor(t, 8, 64);
    t += __shfl_xor(t, 4, 64);
    t += __shfl_xor(t, 2, 64);
    t += __shfl_xor(t, 1, 64);
    if ((threadIdx.x & 63) == 0) wsum[threadIdx.x >> 6] = t;
    __syncthreads();
    if (threadIdx.x == 0) {
        double s = wsum[0] + wsum[1] + wsum[2] + wsum[3];
        *out = (float)(-s * invB);
    }
}

extern "C" void kernel_launch(void* const* d_in, const int* in_sizes, int n_in,
                              void* d_out, int out_size, void* d_ws, size_t ws_size,
                              hipStream_t stream) {
    const float* in_w      = (const float*)d_in[0];
    const float* out_w     = (const float*)d_in[1];
    const int*   in_lab    = (const int*)d_in[2];
    const int*   out_lab   = (const int*)d_in[3];
    const int*   noise_lab = (const int*)d_in[4];

    const int B  = in_sizes[2];   // 4096
    const int BW = in_sizes[3];   // 20480

    float* partials = (float*)d_ws;        // gridDim floats of scratch
    float* out      = (float*)d_out;

    const int blocks = (BW + 3) / 4;       // 4 pairs (waves) per 256-thread block
    neg_loss_kernel<<<blocks, 256, 0, stream>>>(
        in_w, out_w, in_lab, out_lab, noise_lab, partials, B, BW);

    reduce_kernel<<<1, 256, 0, stream>>>(partials, out, blocks, 1.0 / (double)B);
}

// Round 3
// 155.764 us; speedup vs baseline: 1.2319x; 1.0132x over previous
//
#include <hip/hip_runtime.h>
#include <math.h>

// NEG (negative-sampling) loss. V=50000, E=256, B=4096, W=5, S=15.
// Pair j in [0, B*W):
//   inp  = in_embed[input_labels[j % B]]      (tile semantics, NOT interleave)
//   out  = out_embed[out_labels.flat[j]]
//   noise_s = out_embed[noise_labels[j, s]]
//   contrib_j = logsig(<inp,out>) + sum_s logsig(-<inp,noise_s>)
//   loss = -(sum_j contrib_j) / B
//
// R3: same quarter-wave decomposition as R2 (wave = 1 pair, 16 dots = 4 rounds
// x 4 quarter-wave dots; lane t of a quarter owns elements k*64+t*4..+3 ->
// every load is part of a contiguous 256B segment). NEW: all 16 row-loads per
// pair (4 rows/lane x 4 float4) are issued BEFORE any reduction, so one wave
// has 16 global_load_dwordx4 in flight instead of 4 -> 4x memory-level
// parallelism. R2 was latency-bound (VALUBusy 15%, HBM 40%, VGPR 52 = compiler
// serialized the rounds).

#define EDIM 256
#define SNEG 15

__device__ __forceinline__ float dot4(float4 a, float4 b) {
    return a.x * b.x + a.y * b.y + a.z * b.z + a.w * b.w;
}

__device__ __forceinline__ float log_sigmoid_fast(float x) {
    // min(x,0) - log(1 + exp(-|x|)); log arg in (1,2] -> accurate, branch-free
    return fminf(x, 0.0f) - __logf(1.0f + __expf(-fabsf(x)));
}

__global__ __launch_bounds__(256) void neg_loss_kernel(
    const float* __restrict__ in_w,     // [V, E]
    const float* __restrict__ out_w,    // [V, E]
    const int* __restrict__ in_lab,     // [B]
    const int* __restrict__ out_lab,    // [B*W]
    const int* __restrict__ noise_lab,  // [B*W, S]
    float* __restrict__ partials,       // [gridDim.x]
    int B, int BW)
{
    __shared__ float wave_sums[4];
    const int wave = threadIdx.x >> 6;
    const int lane = threadIdx.x & 63;
    const int q    = lane >> 4;   // quarter-wave id
    const int t    = lane & 15;   // position within quarter

    const int j = blockIdx.x * 4 + wave;

    float c = 0.0f;
    if (j < BW) {
        const int jm = (B & (B - 1)) == 0 ? (j & (B - 1)) : (j % B);
        const int in_row = in_lab[jm];
        const int out_row = out_lab[j];
        const int* nl = noise_lab + (size_t)j * SNEG;

        // This lane's 4 dot indices are d = r*4 + q, r=0..3.
        int rows[4];
#pragma unroll
        for (int r = 0; r < 4; ++r) {
            const int d = r * 4 + q;
            rows[r] = (d == 0) ? out_row : nl[d - 1];
        }

        // ---- issue ALL loads first: vin (4) + 4 rows x 4 float4 (16) ----
        const float* vin_base = in_w + (size_t)in_row * EDIM + t * 4;
        float4 vi[4];
#pragma unroll
        for (int k = 0; k < 4; ++k) vi[k] = *(const float4*)(vin_base + k * 64);

        float4 v[4][4];
#pragma unroll
        for (int r = 0; r < 4; ++r) {
            const float* rb = out_w + (size_t)rows[r] * EDIM + t * 4;
#pragma unroll
            for (int k = 0; k < 4; ++k) v[r][k] = *(const float4*)(rb + k * 64);
        }

        // ---- now reduce ----
#pragma unroll
        for (int r = 0; r < 4; ++r) {
            float s = dot4(vi[0], v[r][0]) + dot4(vi[1], v[r][1]) +
                      dot4(vi[2], v[r][2]) + dot4(vi[3], v[r][3]);
            // reduce across the 16 lanes of this quarter
            s += __shfl_xor(s, 1, 64);
            s += __shfl_xor(s, 2, 64);
            s += __shfl_xor(s, 4, 64);
            s += __shfl_xor(s, 8, 64);
            const int d = r * 4 + q;
            c += log_sigmoid_fast((d == 0) ? s : -s);
        }

        // sum the 4 quarter-accumulators across the wave
        c += __shfl_xor(c, 16, 64);
        c += __shfl_xor(c, 32, 64);
    }

    if (lane == 0) wave_sums[wave] = c;
    __syncthreads();
    if (threadIdx.x == 0) {
        partials[blockIdx.x] =
            wave_sums[0] + wave_sums[1] + wave_sums[2] + wave_sums[3];
    }
}

__global__ __launch_bounds__(256) void reduce_kernel(
    const float* __restrict__ partials, float* __restrict__ out,
    int n, double invB)
{
    __shared__ double wsum[4];
    double t = 0.0;
    for (int i = threadIdx.x; i < n; i += 256) t += (double)partials[i];
    t += __shfl_xor(t, 32, 64);
    t += __shfl_xor(t, 16, 64);
    t += __shfl_xor(t, 8, 64);
    t += __shfl_xor(t, 4, 64);
    t += __shfl_xor(t, 2, 64);
    t += __shfl_xor(t, 1, 64);
    if ((threadIdx.x & 63) == 0) wsum[threadIdx.x >> 6] = t;
    __syncthreads();
    if (threadIdx.x == 0) {
        double s = wsum[0] + wsum[1] + wsum[2] + wsum[3];
        *out = (float)(-s * invB);
    }
}

extern "C" void kernel_launch(void* const* d_in, const int* in_sizes, int n_in,
                              void* d_out, int out_size, void* d_ws, size_t ws_size,
                              hipStream_t stream) {
    const float* in_w      = (const float*)d_in[0];
    const float* out_w     = (const float*)d_in[1];
    const int*   in_lab    = (const int*)d_in[2];
    const int*   out_lab   = (const int*)d_in[3];
    const int*   noise_lab = (const int*)d_in[4];

    const int B  = in_sizes[2];   // 4096
    const int BW = in_sizes[3];   // 20480

    float* partials = (float*)d_ws;   // gridDim floats of scratch
    float* out      = (float*)d_out;

    const int blocks = (BW + 3) / 4;  // 4 pairs (waves) per 256-thread block
    neg_loss_kernel<<<blocks, 256, 0, stream>>>(
        in_w, out_w, in_lab, out_lab, noise_lab, partials, B, BW);

    reduce_kernel<<<1, 256, 0, stream>>>(partials, out, blocks, 1.0 / (double)B);
}

// Round 4
// 154.233 us; speedup vs baseline: 1.2441x; 1.0099x over previous
//
#include <hip/hip_runtime.h>
#include <math.h>

// NEG (negative-sampling) loss. V=50000, E=256, B=4096, W=5, S=15.
// Pair j in [0, B*W):
//   inp  = in_embed[input_labels[j % B]]      (tile semantics, NOT interleave)
//   out  = out_embed[out_labels.flat[j]]
//   noise_s = out_embed[noise_labels[j, s]]
//   contrib_j = logsig(<inp,out>) + sum_s logsig(-<inp,noise_s>)
//   loss = -(sum_j contrib_j) / B
//
// R4: R3 was latency-bound with Occupancy=33% despite VGPR=52 (no resource
// limit) -> short-lived blocks + dispatch churn kept residency low. Now:
// 1280 blocks x 256 thr = 5 blocks/CU fully co-resident (20 waves/CU), each
// wave processes EXACTLY 4 pairs via stride loop (5120 waves x 4 = 20480).
// Quarter-wave decomposition per pair unchanged: 16 dots = 4 rounds x 4
// concurrent dots; lane t of a quarter owns elements k*64+t*4 (contiguous
// 256B segments, fully coalesced).

#define EDIM 256
#define SNEG 15

__device__ __forceinline__ float dot4(float4 a, float4 b) {
    return a.x * b.x + a.y * b.y + a.z * b.z + a.w * b.w;
}

__device__ __forceinline__ float log_sigmoid_fast(float x) {
    // min(x,0) - log(1 + exp(-|x|)); log arg in (1,2] -> accurate, branch-free
    return fminf(x, 0.0f) - __logf(1.0f + __expf(-fabsf(x)));
}

__global__ __launch_bounds__(256, 5) void neg_loss_kernel(
    const float* __restrict__ in_w,     // [V, E]
    const float* __restrict__ out_w,    // [V, E]
    const int* __restrict__ in_lab,     // [B]
    const int* __restrict__ out_lab,    // [B*W]
    const int* __restrict__ noise_lab,  // [B*W, S]
    float* __restrict__ partials,       // [gridDim.x]
    int B, int BW)
{
    __shared__ float wave_sums[4];
    const int wave = threadIdx.x >> 6;
    const int lane = threadIdx.x & 63;
    const int q    = lane >> 4;   // quarter-wave id
    const int t    = lane & 15;   // position within quarter

    const int gw = blockIdx.x * 4 + wave;      // global wave id
    const int TW = gridDim.x * 4;              // total waves

    float c = 0.0f;
    for (int j = gw; j < BW; j += TW) {
        const int jm = (B & (B - 1)) == 0 ? (j & (B - 1)) : (j % B);
        const int in_row  = in_lab[jm];
        const int out_row = out_lab[j];
        const int* nl = noise_lab + (size_t)j * SNEG;

        const float* vin_base = in_w + (size_t)in_row * EDIM + t * 4;
        float4 vi[4];
#pragma unroll
        for (int k = 0; k < 4; ++k) vi[k] = *(const float4*)(vin_base + k * 64);

#pragma unroll
        for (int r = 0; r < 4; ++r) {
            const int d = r * 4 + q;                      // dot index 0..15
            const int row = (d == 0) ? out_row : nl[d - 1];
            const float* rb = out_w + (size_t)row * EDIM + t * 4;
            const float4 v0 = *(const float4*)(rb + 0 * 64);
            const float4 v1 = *(const float4*)(rb + 1 * 64);
            const float4 v2 = *(const float4*)(rb + 2 * 64);
            const float4 v3 = *(const float4*)(rb + 3 * 64);

            float s = dot4(vi[0], v0) + dot4(vi[1], v1) +
                      dot4(vi[2], v2) + dot4(vi[3], v3);
            // reduce across the 16 lanes of this quarter
            s += __shfl_xor(s, 1, 64);
            s += __shfl_xor(s, 2, 64);
            s += __shfl_xor(s, 4, 64);
            s += __shfl_xor(s, 8, 64);
            c += log_sigmoid_fast((d == 0) ? s : -s);
        }
    }

    // sum the 4 quarter-accumulators across the wave
    c += __shfl_xor(c, 16, 64);
    c += __shfl_xor(c, 32, 64);

    if (lane == 0) wave_sums[wave] = c;
    __syncthreads();
    if (threadIdx.x == 0) {
        partials[blockIdx.x] =
            wave_sums[0] + wave_sums[1] + wave_sums[2] + wave_sums[3];
    }
}

__global__ __launch_bounds__(256) void reduce_kernel(
    const float* __restrict__ partials, float* __restrict__ out,
    int n, double invB)
{
    __shared__ double wsum[4];
    double t = 0.0;
    for (int i = threadIdx.x; i < n; i += 256) t += (double)partials[i];
    t += __shfl_xor(t, 32, 64);
    t += __shfl_xor(t, 16, 64);
    t += __shfl_xor(t, 8, 64);
    t += __shfl_xor(t, 4, 64);
    t += __shfl_xor(t, 2, 64);
    t += __shfl_xor(t, 1, 64);
    if ((threadIdx.x & 63) == 0) wsum[threadIdx.x >> 6] = t;
    __syncthreads();
    if (threadIdx.x == 0) {
        double s = wsum[0] + wsum[1] + wsum[2] + wsum[3];
        *out = (float)(-s * invB);
    }
}

extern "C" void kernel_launch(void* const* d_in, const int* in_sizes, int n_in,
                              void* d_out, int out_size, void* d_ws, size_t ws_size,
                              hipStream_t stream) {
    const float* in_w      = (const float*)d_in[0];
    const float* out_w     = (const float*)d_in[1];
    const int*   in_lab    = (const int*)d_in[2];
    const int*   out_lab   = (const int*)d_in[3];
    const int*   noise_lab = (const int*)d_in[4];

    const int B  = in_sizes[2];   // 4096
    const int BW = in_sizes[3];   // 20480

    float* partials = (float*)d_ws;   // gridDim floats of scratch
    float* out      = (float*)d_out;

    // 1280 blocks = 5 blocks/CU co-resident; 5120 waves x exactly 4 pairs.
    const int blocks = 1280;
    neg_loss_kernel<<<blocks, 256, 0, stream>>>(
        in_w, out_w, in_lab, out_lab, noise_lab, partials, B, BW);

    reduce_kernel<<<1, 256, 0, stream>>>(partials, out, blocks, 1.0 / (double)B);
}